// Round 6
// baseline (335.911 us; speedup 1.0000x reference)
//
#include <hip/hip_runtime.h>
#include <stdint.h>

typedef unsigned short u16;
typedef __bf16 bf16x8 __attribute__((ext_vector_type(8)));
typedef float  f32x4  __attribute__((ext_vector_type(4)));

// ---- problem constants ----
#define SDIM 2048
#define BDIM 8
#define DIN  1024
#define DOUT 4096
#define EDIM 8
#define RDIM 16
#define KAUG 1152            // DIN + E*R
#define MDIM (SDIM*BDIM)     // 16384
#define SCH  32
#define NT2  18              // K-tiles of 64
#define ITERS 9              // 2 K-tiles per iter

__device__ __forceinline__ u16 f2bf(float f) {
    __bf16 h = (__bf16)f;
    return __builtin_bit_cast(u16, h);
}

__device__ __forceinline__ void gload16(const u16* g, u16* lds) {
    __builtin_amdgcn_global_load_lds(
        (const __attribute__((address_space(1))) void*)g,
        (__attribute__((address_space(3))) void*)lds, 16, 0, 0);
}

#define VMCNT(n)  asm volatile("s_waitcnt vmcnt(" #n ")" ::: "memory")
#define LGKM(n)   asm volatile("s_waitcnt lgkmcnt(" #n ")" ::: "memory")
#define BARF()    do { asm volatile("" ::: "memory");                \
                       __builtin_amdgcn_s_barrier();                 \
                       asm volatile("" ::: "memory"); } while (0)

// ---------------------------------------------------------------------------
// k1: per-(b, s-chunk) partial sums of x over s + bf16 convert into Xb
// ---------------------------------------------------------------------------
__global__ __launch_bounds__(256) void k1_reduce_convert(
    const float* __restrict__ x, u16* __restrict__ Xb, float* __restrict__ P)
{
    const int b  = blockIdx.x;
    const int sc = blockIdx.y;
    const int i  = threadIdx.x * 4;
    float a0 = 0.f, a1 = 0.f, a2 = 0.f, a3 = 0.f;
    const int s0 = sc * (SDIM / SCH);
    for (int s = s0; s < s0 + (SDIM / SCH); ++s) {
        const float4 v = *reinterpret_cast<const float4*>(
            &x[((size_t)s * BDIM + b) * DIN + i]);
        a0 += v.x; a1 += v.y; a2 += v.z; a3 += v.w;
        ushort4 u{f2bf(v.x), f2bf(v.y), f2bf(v.z), f2bf(v.w)};
        *reinterpret_cast<ushort4*>(&Xb[((size_t)s * BDIM + b) * KAUG + i]) = u;
    }
    float4 p{a0, a1, a2, a3};
    *reinterpret_cast<float4*>(&P[((size_t)sc * BDIM + b) * DIN + i]) = p;
}

// ---------------------------------------------------------------------------
// k2: gate weights
// ---------------------------------------------------------------------------
__global__ __launch_bounds__(256) void k2_gates(
    const float* __restrict__ P, const float* __restrict__ gw,
    const float* __restrict__ gb, float* __restrict__ g)
{
    const int e = blockIdx.x, b = blockIdx.y, t = threadIdx.x;
    float dot = 0.f;
    for (int i = t; i < DIN; i += 256) {
        float xs = 0.f;
        #pragma unroll
        for (int c = 0; c < SCH; ++c) xs += P[((size_t)c * BDIM + b) * DIN + i];
        dot += xs * gw[(size_t)e * DIN + i];
    }
    __shared__ float red[256];
    red[t] = dot;
    __syncthreads();
    #pragma unroll
    for (int off = 128; off > 0; off >>= 1) {
        if (t < off) red[t] += red[t + off];
        __syncthreads();
    }
    if (t == 0) g[b * EDIM + e] = red[0] * (1.0f / SDIM) + gb[e];
}

// ---------------------------------------------------------------------------
// kw: build Waug
// ---------------------------------------------------------------------------
__global__ __launch_bounds__(256) void kw_build_waug(
    const float* __restrict__ W, const float* __restrict__ lb, u16* __restrict__ Waug)
{
    const int o = blockIdx.x, t = threadIdx.x;
    for (int i = t; i < DIN; i += 256)
        Waug[(size_t)o * KAUG + i] = f2bf(W[(size_t)o * DIN + i]);
    if (t < EDIM * RDIM) {
        const int e = t >> 4, r = t & 15;
        Waug[(size_t)o * KAUG + DIN + t] =
            f2bf(lb[((size_t)e * DOUT + o) * RDIM + r]);
    }
}

__global__ __launch_bounds__(256) void kl_convert(
    const float* __restrict__ la, u16* __restrict__ LAb)
{
    const int idx = blockIdx.x * 256 + threadIdx.x;
    if (idx < EDIM * RDIM * DIN) LAb[idx] = f2bf(la[idx]);
}

__global__ __launch_bounds__(256) void k4_scale_u(
    const float* __restrict__ T, const float* __restrict__ g, u16* __restrict__ Xb)
{
    const int idx = blockIdx.x * 256 + threadIdx.x;
    const int m = idx >> 7, er = idx & 127;
    const int b = m & (BDIM - 1), e = er >> 4;
    const float u = g[b * EDIM + e] * T[idx];
    Xb[(size_t)m * KAUG + DIN + er] = f2bf(u);
}

// ---------------------------------------------------------------------------
// gemm_bt: R0 128x128 kernel — used only for the small LoRA GEMM (N=128)
// ---------------------------------------------------------------------------
template <int ADD_BIAS>
__global__ __launch_bounds__(256) void gemm_bt(
    const u16* __restrict__ A, int lda,
    const u16* __restrict__ B, int ldb,
    float* __restrict__ C, int ldc,
    const float* __restrict__ bias, int ktiles)
{
    __shared__ __align__(16) u16 As[8][128][8];
    __shared__ __align__(16) u16 Bs[8][128][8];

    const int tid  = threadIdx.x;
    const int lane = tid & 63;
    const int l15  = lane & 15;
    const int l4   = lane >> 4;
    const int wid  = tid >> 6;
    const int wr   = wid >> 1;
    const int wc   = wid & 1;
    const int m0 = blockIdx.y * 128;
    const int n0 = blockIdx.x * 128;
    const int mr  = tid & 127;
    const int chi = tid >> 7;

    f32x4 acc[4][4] = {};

    for (int kt = 0; kt < ktiles; ++kt) {
        #pragma unroll
        for (int q = 0; q < 4; ++q) {
            const int c    = q * 2 + chi;
            const int kofs = kt * 64 + c * 8;
            u16* ldsbase   = (u16*)As + (size_t)(q * 256 + (tid & 192)) * 8;
            gload16(A + (size_t)(m0 + mr) * lda + kofs, ldsbase);
            u16* ldsbaseB  = (u16*)Bs + (size_t)(q * 256 + (tid & 192)) * 8;
            gload16(B + (size_t)(n0 + mr) * ldb + kofs, ldsbaseB);
        }
        __syncthreads();
        #pragma unroll
        for (int ks = 0; ks < 2; ++ks) {
            const int c = ks * 4 + l4;
            bf16x8 av[4], bv[4];
            #pragma unroll
            for (int mi = 0; mi < 4; ++mi)
                av[mi] = *reinterpret_cast<const bf16x8*>(
                    &As[c][wr * 64 + mi * 16 + l15][0]);
            #pragma unroll
            for (int ni = 0; ni < 4; ++ni)
                bv[ni] = *reinterpret_cast<const bf16x8*>(
                    &Bs[c][wc * 64 + ni * 16 + l15][0]);
            #pragma unroll
            for (int mi = 0; mi < 4; ++mi)
                #pragma unroll
                for (int ni = 0; ni < 4; ++ni)
                    acc[mi][ni] = __builtin_amdgcn_mfma_f32_16x16x32_bf16(
                        av[mi], bv[ni], acc[mi][ni], 0, 0, 0);
        }
        __syncthreads();
    }

    #pragma unroll
    for (int mi = 0; mi < 4; ++mi) {
        const int r0 = m0 + wr * 64 + mi * 16 + l4 * 4;
        #pragma unroll
        for (int ni = 0; ni < 4; ++ni) {
            const int col = n0 + wc * 64 + ni * 16 + l15;
            const float badd = ADD_BIAS ? bias[col] : 0.0f;
            float* cp = C + (size_t)r0 * ldc + col;
            #pragma unroll
            for (int r = 0; r < 4; ++r)
                cp[(size_t)r * ldc] = acc[mi][ni][r] + badd;
        }
    }
}

// ---------------------------------------------------------------------------
// gemm_main R5: faithful m201 8-phase template.
// BM=BN=256, BK=64, 2 tiles/iter (ITERS=9), 512 thr (8 waves 2Mx4N,
// per-wave 128x64), dbuf LDS 128 KiB, k-slab layout (0 conflicts, PMC R0-R4).
//
// Phase = {ds_read subtile; stage; [lgkm(8) if 12 reads]; [VMCNT gate @p3/p7];
//          BAR; lgkm(0); sched_barrier(0); prio1; 16 MFMA; prio0; BAR}
// Quadrant walk per tile (a-group g, b-pair q): (0,0) (0,1) (1,1) (1,0)
//   -> reads 12/4/8/4 per phase (A-group 8, B-pair 4; B01 re-read at p3).
//
// Stage schedule (half-tile HT = A-half or B-half, 2 gloads each; one PAIR
// per designated phase). Last-read phases per window [p0-p3 even tile]:
// A-halves p2, B-halves p3 (odd window: p6/p7). Safe stage = next phase.
//   p0: B(2i+1) both | p3: A(2i+2) both | p4: B(2i+2) both | p7: A(2i+3) both
// First-read leads are 4 phases; gload lands async, reads gated by:
// vmcnt ledger (VMCNT placed AFTER that phase's stage, BEFORE its B1; the
// barrier makes the per-wave vmcnt a global guarantee):
//   @p3: outstanding = A(2i+1)@p7(i-1) 4 + B(2i+1)@p0 4 + A(2i+2)@p3 4 = 12
//        VMCNT(4) confirms tile 2i+1 complete (leaves p3's 4 in flight)
//   @p7: outstanding = A(2i+2)@p3 4 + B(2i+2)@p4 4 + A(2i+3)@p7 4 = 12
//        VMCNT(4) confirms tile 2i+2 complete (leaves p7's 4)
// Tail i=8: stages for tiles>=18 skipped; gates -> VMCNT(0).
// WAR: stage at phase q overwrites a region whose last read was phase q-1;
// lgkm(0) before each MFMA + the end-phase barrier guarantee all waves'
// reads complete before any wave issues the overwriting stage.
// Prologue: A(0),B(0),A(1) = 12 loads; VMCNT(4) confirms tile 0; BAR.
// ---------------------------------------------------------------------------
__global__ __launch_bounds__(512) void gemm_main(
    const u16* __restrict__ A, const u16* __restrict__ B,
    float* __restrict__ C, const float* __restrict__ bias)
{
    __shared__ __align__(16) u16 As[2][2][8][128][8];   // [buf][Mhalf][slab][row][8] 64K
    __shared__ __align__(16) u16 Bs[2][2][8][128][8];   // [buf][Nhalf][slab][row][8] 64K

    const int tid  = threadIdx.x;
    const int lane = tid & 63;
    const int l15  = lane & 15;
    const int l4   = lane >> 4;
    const int wid  = tid >> 6;      // 0..7
    const int wm   = wid >> 2;      // 0..1  (128-row half; = A Mhalf this wave reads)
    const int wn   = wid & 3;       // 0..3  (64-col quarter)
    const int bh   = wn >> 1;       // B Nhalf this wave reads
    const int bl   = wn & 1;        // 64-row block within that half

    // T1: XCD-aware swizzle (nwg = 16*64 = 1024, % 8 == 0)
    const int f   = blockIdx.x + blockIdx.y * gridDim.x;
    const int cpx = (gridDim.x * gridDim.y) >> 3;
    const int s_  = (f & 7) * cpx + (f >> 3);
    const int m0  = (s_ / gridDim.x) * 256;
    const int n0  = (s_ % gridDim.x) * 256;

    f32x4  acc[8][4] = {};
    bf16x8 aval[4][2], bval[2][2];

    auto stageA = [&](int t, int h) {
        const int buf = t & 1;
        #pragma unroll
        for (int ii = 0; ii < 2; ++ii) {
            const int cix = ii * 512 + tid;
            const int row = cix & 127, slab = cix >> 7;
            gload16(A + (size_t)(m0 + h * 128 + row) * KAUG + t * 64 + slab * 8,
                    &As[buf][h][slab][row][0]);
        }
    };
    auto stageB = [&](int t, int h) {
        const int buf = t & 1;
        #pragma unroll
        for (int ii = 0; ii < 2; ++ii) {
            const int cix = ii * 512 + tid;
            const int row = cix & 127, slab = cix >> 7;
            gload16(B + (size_t)(n0 + h * 128 + row) * KAUG + t * 64 + slab * 8,
                    &Bs[buf][h][slab][row][0]);
        }
    };

    // reads: a-group G (0=frags0-3, 1=frags4-7), b-pair Q (0=nf01, 1=nf23)
    #define RD_A(BUF, G)                                                      \
        _Pragma("unroll") for (int fr = 0; fr < 4; ++fr)                      \
            _Pragma("unroll") for (int kk = 0; kk < 2; ++kk)                  \
                aval[fr][kk] = *reinterpret_cast<const bf16x8*>(              \
                    &As[BUF][wm][kk * 4 + l4][(G) * 64 + fr * 16 + l15][0]);
    #define RD_B(BUF, Q)                                                      \
        _Pragma("unroll") for (int jj = 0; jj < 2; ++jj)                      \
            _Pragma("unroll") for (int kk = 0; kk < 2; ++kk)                  \
                bval[jj][kk] = *reinterpret_cast<const bf16x8*>(              \
                    &Bs[BUF][bh][kk * 4 + l4][bl * 64 + ((Q) * 2 + jj) * 16 + l15][0]);
    #define MMQ(G, Q)                                                         \
        do {                                                                  \
            LGKM(0);                                                          \
            __builtin_amdgcn_sched_barrier(0);                                \
            __builtin_amdgcn_s_setprio(1);                                    \
            _Pragma("unroll") for (int kk = 0; kk < 2; ++kk)                  \
                _Pragma("unroll") for (int fr = 0; fr < 4; ++fr)              \
                    _Pragma("unroll") for (int jj = 0; jj < 2; ++jj)          \
                        acc[(G) * 4 + fr][(Q) * 2 + jj] =                     \
                            __builtin_amdgcn_mfma_f32_16x16x32_bf16(          \
                                aval[fr][kk], bval[jj][kk],                   \
                                acc[(G) * 4 + fr][(Q) * 2 + jj], 0, 0, 0);    \
            __builtin_amdgcn_s_setprio(0);                                    \
        } while (0)

    // prologue: tile0 (A,B) + tile1 (A) = 12 loads; confirm tile0, 4 in flight
    stageA(0, 0); stageA(0, 1); stageB(0, 0); stageB(0, 1);
    stageA(1, 0); stageA(1, 1);
    VMCNT(4);
    BARF();

    for (int i = 0; i < ITERS; ++i) {
        const int t1 = 2 * i + 1;
        const bool st = (i < ITERS - 1);
        // ---- p0: tile 2i, quad (0,0) ----
        RD_A(0, 0); RD_B(0, 0);
        stageB(t1, 0); stageB(t1, 1);
        LGKM(8);
        BARF(); MMQ(0, 0); BARF();
        // ---- p1: quad (0,1) ----
        RD_B(0, 1);
        BARF(); MMQ(0, 1); BARF();
        // ---- p2: quad (1,1) ----
        RD_A(0, 1);
        BARF(); MMQ(1, 1); BARF();
        // ---- p3: quad (1,0); stage A(2i+2); gate tile 2i+1 ----
        RD_B(0, 0);
        if (st) { stageA(t1 + 1, 0); stageA(t1 + 1, 1); VMCNT(4); }
        else    { VMCNT(0); }
        BARF(); MMQ(1, 0); BARF();
        // ---- p4: tile 2i+1, quad (0,0); stage B(2i+2) ----
        RD_A(1, 0); RD_B(1, 0);
        if (st) { stageB(t1 + 1, 0); stageB(t1 + 1, 1); }
        LGKM(8);
        BARF(); MMQ(0, 0); BARF();
        // ---- p5: quad (0,1) ----
        RD_B(1, 1);
        BARF(); MMQ(0, 1); BARF();
        // ---- p6: quad (1,1) ----
        RD_A(1, 1);
        BARF(); MMQ(1, 1); BARF();
        // ---- p7: quad (1,0); stage A(2i+3); gate tile 2i+2 ----
        RD_B(1, 0);
        if (st) { stageA(t1 + 2, 0); stageA(t1 + 2, 1); VMCNT(4); }
        else    { VMCNT(0); }
        BARF(); MMQ(1, 0); BARF();
    }
    #undef RD_A
    #undef RD_B
    #undef MMQ

    // ---- epilogue: row=(l>>4)*4+reg, col=l&15 per fragment ----
    #pragma unroll
    for (int a = 0; a < 8; ++a) {
        const int row0 = m0 + wm * 128 + a * 16 + l4 * 4;
        #pragma unroll
        for (int nf = 0; nf < 4; ++nf) {
            const int col = n0 + wn * 64 + nf * 16 + l15;
            const float badd = bias[col];
            float* cp = C + (size_t)row0 * DOUT + col;
            #pragma unroll
            for (int q = 0; q < 4; ++q)
                cp[(size_t)q * DOUT] = acc[a][nf][q] + badd;
        }
    }
}

// ---------------------------------------------------------------------------
extern "C" void kernel_launch(void* const* d_in, const int* in_sizes, int n_in,
                              void* d_out, int out_size, void* d_ws, size_t ws_size,
                              hipStream_t stream)
{
    const float* x    = (const float*)d_in[0];
    const float* gw   = (const float*)d_in[1];
    const float* gb   = (const float*)d_in[2];
    const float* W    = (const float*)d_in[3];
    const float* bias = (const float*)d_in[4];
    const float* la   = (const float*)d_in[5];
    const float* lb   = (const float*)d_in[6];
    float* out = (float*)d_out;

    char* ws = (char*)d_ws;
    u16*   Xb   = (u16*)(ws);                       // 37,748,736 B
    u16*   Waug = (u16*)(ws + 37748736);            //  9,437,184 B
    float* T    = (float*)(ws + 47185920);          //  8,388,608 B
    float* P    = (float*)(ws + 55574528);          //  1,048,576 B
    u16*   LAb  = (u16*)(ws + 56623104);            //    262,144 B
    float* G    = (float*)(ws + 56885248);          //        256 B

    k1_reduce_convert<<<dim3(BDIM, SCH), 256, 0, stream>>>(x, Xb, P);
    kw_build_waug<<<DOUT, 256, 0, stream>>>(W, lb, Waug);
    kl_convert<<<(EDIM * RDIM * DIN + 255) / 256, 256, 0, stream>>>(la, LAb);
    k2_gates<<<dim3(EDIM, BDIM), 256, 0, stream>>>(P, gw, gb, G);
    gemm_bt<0><<<dim3(1, MDIM / 128), 256, 0, stream>>>(
        Xb, KAUG, LAb, DIN, T, EDIM * RDIM, nullptr, DIN / 64);
    k4_scale_u<<<(MDIM * EDIM * RDIM) / 256, 256, 0, stream>>>(T, G, Xb);
    gemm_main<<<dim3(DOUT / 256, MDIM / 256), 512, 0, stream>>>(
        Xb, Waug, out, bias);
}

// Round 9
// 239.839 us; speedup vs baseline: 1.4006x; 1.4006x over previous
//
#include <hip/hip_runtime.h>
#include <stdint.h>

typedef unsigned short u16;
typedef __bf16 bf16x8 __attribute__((ext_vector_type(8)));
typedef float  f32x4  __attribute__((ext_vector_type(4)));

// ---- problem constants ----
#define SDIM 2048
#define BDIM 8
#define DIN  1024
#define DOUT 4096
#define EDIM 8
#define RDIM 16
#define KAUG 1152            // DIN + E*R
#define MDIM (SDIM*BDIM)     // 16384
#define SCH  32
#define NT2  18              // K-tiles of 64 for the main GEMM

__device__ __forceinline__ u16 f2bf(float f) {
    __bf16 h = (__bf16)f;
    return __builtin_bit_cast(u16, h);
}

__device__ __forceinline__ void gload16(const u16* g, u16* lds) {
    __builtin_amdgcn_global_load_lds(
        (const __attribute__((address_space(1))) void*)g,
        (__attribute__((address_space(3))) void*)lds, 16, 0, 0);
}

#define VMCNT(n)  asm volatile("s_waitcnt vmcnt(" #n ")" ::: "memory")
#define BARF()    do { asm volatile("" ::: "memory");                \
                       __builtin_amdgcn_s_barrier();                 \
                       asm volatile("" ::: "memory"); } while (0)

// ---------------------------------------------------------------------------
// k1: per-(b, s-chunk) partial sums of x over s + bf16 convert into Xb
// ---------------------------------------------------------------------------
__global__ __launch_bounds__(256) void k1_reduce_convert(
    const float* __restrict__ x, u16* __restrict__ Xb, float* __restrict__ P)
{
    const int b  = blockIdx.x;
    const int sc = blockIdx.y;
    const int i  = threadIdx.x * 4;
    float a0 = 0.f, a1 = 0.f, a2 = 0.f, a3 = 0.f;
    const int s0 = sc * (SDIM / SCH);
    for (int s = s0; s < s0 + (SDIM / SCH); ++s) {
        const float4 v = *reinterpret_cast<const float4*>(
            &x[((size_t)s * BDIM + b) * DIN + i]);
        a0 += v.x; a1 += v.y; a2 += v.z; a3 += v.w;
        ushort4 u{f2bf(v.x), f2bf(v.y), f2bf(v.z), f2bf(v.w)};
        *reinterpret_cast<ushort4*>(&Xb[((size_t)s * BDIM + b) * KAUG + i]) = u;
    }
    float4 p{a0, a1, a2, a3};
    *reinterpret_cast<float4*>(&P[((size_t)sc * BDIM + b) * DIN + i]) = p;
}

// ---------------------------------------------------------------------------
// k2: gate weights
// ---------------------------------------------------------------------------
__global__ __launch_bounds__(256) void k2_gates(
    const float* __restrict__ P, const float* __restrict__ gw,
    const float* __restrict__ gb, float* __restrict__ g)
{
    const int e = blockIdx.x, b = blockIdx.y, t = threadIdx.x;
    float dot = 0.f;
    for (int i = t; i < DIN; i += 256) {
        float xs = 0.f;
        #pragma unroll
        for (int c = 0; c < SCH; ++c) xs += P[((size_t)c * BDIM + b) * DIN + i];
        dot += xs * gw[(size_t)e * DIN + i];
    }
    __shared__ float red[256];
    red[t] = dot;
    __syncthreads();
    #pragma unroll
    for (int off = 128; off > 0; off >>= 1) {
        if (t < off) red[t] += red[t + off];
        __syncthreads();
    }
    if (t == 0) g[b * EDIM + e] = red[0] * (1.0f / SDIM) + gb[e];
}

// ---------------------------------------------------------------------------
// kw: build Waug
// ---------------------------------------------------------------------------
__global__ __launch_bounds__(256) void kw_build_waug(
    const float* __restrict__ W, const float* __restrict__ lb, u16* __restrict__ Waug)
{
    const int o = blockIdx.x, t = threadIdx.x;
    for (int i = t; i < DIN; i += 256)
        Waug[(size_t)o * KAUG + i] = f2bf(W[(size_t)o * DIN + i]);
    if (t < EDIM * RDIM) {
        const int e = t >> 4, r = t & 15;
        Waug[(size_t)o * KAUG + DIN + t] =
            f2bf(lb[((size_t)e * DOUT + o) * RDIM + r]);
    }
}

__global__ __launch_bounds__(256) void kl_convert(
    const float* __restrict__ la, u16* __restrict__ LAb)
{
    const int idx = blockIdx.x * 256 + threadIdx.x;
    if (idx < EDIM * RDIM * DIN) LAb[idx] = f2bf(la[idx]);
}

__global__ __launch_bounds__(256) void k4_scale_u(
    const float* __restrict__ T, const float* __restrict__ g, u16* __restrict__ Xb)
{
    const int idx = blockIdx.x * 256 + threadIdx.x;
    const int m = idx >> 7, er = idx & 127;
    const int b = m & (BDIM - 1), e = er >> 4;
    const float u = g[b * EDIM + e] * T[idx];
    Xb[(size_t)m * KAUG + DIN + er] = f2bf(u);
}

// ---------------------------------------------------------------------------
// gemm_bt R6: 128x128 tile, BK=64 — small LoRA GEMM (N=128).
// LDS layout: row-major [128][64] with (row&7) chunk-XOR swizzle.
// Staging: lane cix writes linear LDS slot cix; global src chunk =
// (cix&7)^(row&7) of row cix>>3  => 8 lanes read one 128-B row segment
// (8 cache lines / wave-inst, fully coalesced — fixes the 64-line scatter).
// Reads: chunk_log = ks*4+l4, phys = chunk_log ^ (lane&7): 16 lanes spread
// over 8 bank-quads, 2-way aliasing = free (m136).
// ---------------------------------------------------------------------------
template <int ADD_BIAS>
__global__ __launch_bounds__(256) void gemm_bt(
    const u16* __restrict__ A, int lda,
    const u16* __restrict__ B, int ldb,
    float* __restrict__ C, int ldc,
    const float* __restrict__ bias, int ktiles)
{
    __shared__ __align__(16) u16 As[128][64];
    __shared__ __align__(16) u16 Bs[128][64];

    const int tid  = threadIdx.x;
    const int lane = tid & 63;
    const int l15  = lane & 15;
    const int l4   = lane >> 4;
    const int sw   = lane & 7;
    const int wid  = tid >> 6;
    const int wr   = wid >> 1;
    const int wc   = wid & 1;
    const int m0 = blockIdx.y * 128;
    const int n0 = blockIdx.x * 128;

    f32x4 acc[4][4] = {};

    for (int kt = 0; kt < ktiles; ++kt) {
        #pragma unroll
        for (int ii = 0; ii < 4; ++ii) {
            const int cix = ii * 256 + tid;
            const int row = cix >> 3, cl = cix & 7;
            const int kof = kt * 64 + ((cl ^ (row & 7)) << 3);
            gload16(A + (size_t)(m0 + row) * lda + kof, &As[0][0] + cix * 8);
            gload16(B + (size_t)(n0 + row) * ldb + kof, &Bs[0][0] + cix * 8);
        }
        __syncthreads();
        #pragma unroll
        for (int ks = 0; ks < 2; ++ks) {
            bf16x8 av[4], bv[4];
            #pragma unroll
            for (int mi = 0; mi < 4; ++mi)
                av[mi] = *reinterpret_cast<const bf16x8*>(
                    &As[wr * 64 + mi * 16 + l15][((ks * 4 + l4) ^ sw) << 3]);
            #pragma unroll
            for (int ni = 0; ni < 4; ++ni)
                bv[ni] = *reinterpret_cast<const bf16x8*>(
                    &Bs[wc * 64 + ni * 16 + l15][((ks * 4 + l4) ^ sw) << 3]);
            #pragma unroll
            for (int mi = 0; mi < 4; ++mi)
                #pragma unroll
                for (int ni = 0; ni < 4; ++ni)
                    acc[mi][ni] = __builtin_amdgcn_mfma_f32_16x16x32_bf16(
                        av[mi], bv[ni], acc[mi][ni], 0, 0, 0);
        }
        __syncthreads();
    }

    #pragma unroll
    for (int mi = 0; mi < 4; ++mi) {
        const int r0 = m0 + wr * 64 + mi * 16 + l4 * 4;
        #pragma unroll
        for (int ni = 0; ni < 4; ++ni) {
            const int col = n0 + wc * 64 + ni * 16 + l15;
            const float badd = ADD_BIAS ? bias[col] : 0.0f;
            float* cp = C + (size_t)r0 * ldc + col;
            #pragma unroll
            for (int r = 0; r < 4; ++r)
                cp[(size_t)r * ldc] = acc[mi][ni][r] + badd;
        }
    }
}

// ---------------------------------------------------------------------------
// gemm_main R6: R4's 4-phase schedule (best so far) + COALESCED staging layout.
// BM=BN=256, BK=64, NT2=18, 512 thr (8 waves 2Mx4N, per-wave 128x64),
// dbuf LDS 128 KiB.
// LDS: row-major halves [buf][half][128][64] u16, (row&7) chunk-XOR swizzle.
//   stage: lane cix -> linear LDS slot cix, global chunk (cix&7)^(row&7) of
//     row cix>>3: 8 lanes = one 128-B aligned row segment => 8 cache lines
//     per wave-inst (was 64 with the k-slab layout: 2304-B lane stride, the
//     ~2.7x staging-TA bottleneck identified from R2/R4/R5 tile arithmetic).
//   read: phys_chunk = (kk*4+l4)^(lane&7): 2-way bank aliasing = free.
// Stage unit = half-tile (16 KB, 2 gloads/thread); units u, u%4:{A0,A1,B0,B1},
// buf=(u>>2)&1; one unit per phase, lead 5 (su = 4j+5+P).
// vmcnt ledger: at p3 of tile j issued through unit 4j+8; VMCNT(2) leaves
// unit 4j+8 in flight, confirms tile j+1 (units <=4j+7). Tail: VMCNT(0) at
// j>=NT2-2. Prologue: units 0..4, VMCNT(2) confirms tile 0.
// ---------------------------------------------------------------------------
__global__ __launch_bounds__(512) void gemm_main(
    const u16* __restrict__ A, const u16* __restrict__ Bm,
    float* __restrict__ C, const float* __restrict__ bias)
{
    __shared__ __align__(16) u16 As[2][2][128][64];   // [buf][Mhalf][row][k] 64 KiB
    __shared__ __align__(16) u16 Bs[2][2][128][64];   // [buf][Nhalf][row][k] 64 KiB

    const int tid  = threadIdx.x;
    const int lane = tid & 63;
    const int l15  = lane & 15;
    const int l4   = lane >> 4;
    const int sw   = lane & 7;
    const int wid  = tid >> 6;      // 0..7
    const int wm   = wid >> 2;      // 0..1  (128-row half)
    const int wn   = wid & 3;       // 0..3  (64-col quarter)
    const int bh   = wn >> 1;       // B Nhalf
    const int bl   = wn & 1;        // 64-row block within half

    // T1: XCD-aware swizzle (nwg = 16*64 = 1024, % 8 == 0)
    const int f   = blockIdx.x + blockIdx.y * gridDim.x;
    const int cpx = (gridDim.x * gridDim.y) >> 3;
    const int s_  = (f & 7) * cpx + (f >> 3);
    const int m0  = (s_ / gridDim.x) * 256;
    const int n0  = (s_ % gridDim.x) * 256;

    f32x4  acc[8][4] = {};
    bf16x8 aq[2][2], bv[4][2];

    auto stage = [&](int s) {
        const int t = s >> 2, part = s & 3, buf = t & 1, hf = part & 1;
        #pragma unroll
        for (int ii = 0; ii < 2; ++ii) {
            const int cix = ii * 512 + tid;
            const int row = cix >> 3, cl = cix & 7;
            const int kof = t * 64 + ((cl ^ (row & 7)) << 3);
            if (part < 2)
                gload16(A + (size_t)(m0 + hf * 128 + row) * KAUG + kof,
                        &As[buf][hf][0][0] + cix * 8);
            else
                gload16(Bm + (size_t)(n0 + hf * 128 + row) * KAUG + kof,
                        &Bs[buf][hf][0][0] + cix * 8);
        }
    };

    // prologue: units 0..4 (tile 0 fully + A-h0 of tile 1) = 10 gloads
    stage(0); stage(1); stage(2); stage(3); stage(4);
    VMCNT(2);                       // confirm units 0..3 (tile 0); unit 4 in flight
    BARF();

    #define PHASE(P)                                                            \
    do {                                                                        \
        if ((P) == 0) {                                                         \
            _Pragma("unroll") for (int nf = 0; nf < 4; ++nf)                    \
                _Pragma("unroll") for (int kk = 0; kk < 2; ++kk)                \
                    bv[nf][kk] = *reinterpret_cast<const bf16x8*>(              \
                        &Bs[buf][bh][bl * 64 + nf * 16 + l15]                   \
                           [((kk * 4 + l4) ^ sw) << 3]);                        \
        }                                                                       \
        _Pragma("unroll") for (int fr = 0; fr < 2; ++fr)                        \
            _Pragma("unroll") for (int kk = 0; kk < 2; ++kk)                    \
                aq[fr][kk] = *reinterpret_cast<const bf16x8*>(                  \
                    &As[buf][wm][(P) * 32 + fr * 16 + l15]                      \
                       [((kk * 4 + l4) ^ sw) << 3]);                            \
        { const int su = 4 * j + 5 + (P); if (su < 4 * NT2) stage(su); }        \
        __builtin_amdgcn_s_setprio(1);                                          \
        _Pragma("unroll") for (int kk = 0; kk < 2; ++kk)                        \
            _Pragma("unroll") for (int fr = 0; fr < 2; ++fr)                    \
                _Pragma("unroll") for (int nf = 0; nf < 4; ++nf)                \
                    acc[(P) * 2 + fr][nf] =                                     \
                        __builtin_amdgcn_mfma_f32_16x16x32_bf16(                \
                            aq[fr][kk], bv[nf][kk], acc[(P) * 2 + fr][nf],      \
                            0, 0, 0);                                           \
        __builtin_amdgcn_s_setprio(0);                                          \
        if ((P) == 3) { if (j < NT2 - 2) VMCNT(2); else VMCNT(0); }             \
        BARF();                                                                 \
    } while (0)

    for (int j = 0; j < NT2; ++j) {
        const int buf = j & 1;
        PHASE(0);
        PHASE(1);
        PHASE(2);
        PHASE(3);
    }
    #undef PHASE

    // ---- epilogue: row = wm*128 + a*16 + l4*4, col per fragment ----
    #pragma unroll
    for (int a = 0; a < 8; ++a) {
        const int row0 = m0 + wm * 128 + a * 16 + l4 * 4;
        #pragma unroll
        for (int nf = 0; nf < 4; ++nf) {
            const int col = n0 + wn * 64 + nf * 16 + l15;
            const float badd = bias[col];
            float* cp = C + (size_t)row0 * DOUT + col;
            #pragma unroll
            for (int q = 0; q < 4; ++q)
                cp[(size_t)q * DOUT] = acc[a][nf][q] + badd;
        }
    }
}

// ---------------------------------------------------------------------------
extern "C" void kernel_launch(void* const* d_in, const int* in_sizes, int n_in,
                              void* d_out, int out_size, void* d_ws, size_t ws_size,
                              hipStream_t stream)
{
    const float* x    = (const float*)d_in[0];
    const float* gw   = (const float*)d_in[1];
    const float* gb   = (const float*)d_in[2];
    const float* W    = (const float*)d_in[3];
    const float* bias = (const float*)d_in[4];
    const float* la   = (const float*)d_in[5];
    const float* lb   = (const float*)d_in[6];
    float* out = (float*)d_out;

    char* ws = (char*)d_ws;
    u16*   Xb   = (u16*)(ws);                       // 37,748,736 B
    u16*   Waug = (u16*)(ws + 37748736);            //  9,437,184 B
    float* T    = (float*)(ws + 47185920);          //  8,388,608 B
    float* P    = (float*)(ws + 55574528);          //  1,048,576 B
    u16*   LAb  = (u16*)(ws + 56623104);            //    262,144 B
    float* G    = (float*)(ws + 56885248);          //        256 B

    k1_reduce_convert<<<dim3(BDIM, SCH), 256, 0, stream>>>(x, Xb, P);
    kw_build_waug<<<DOUT, 256, 0, stream>>>(W, lb, Waug);
    kl_convert<<<(EDIM * RDIM * DIN + 255) / 256, 256, 0, stream>>>(la, LAb);
    k2_gates<<<dim3(EDIM, BDIM), 256, 0, stream>>>(P, gw, gb, G);
    gemm_bt<0><<<dim3(1, MDIM / 128), 256, 0, stream>>>(
        Xb, KAUG, LAb, DIN, T, EDIM * RDIM, nullptr, DIN / 64);
    k4_scale_u<<<(MDIM * EDIM * RDIM) / 256, 256, 0, stream>>>(T, G, Xb);
    gemm_main<<<dim3(DOUT / 256, MDIM / 256), 512, 0, stream>>>(
        Xb, Waug, out, bias);
}

// Round 10
// 239.554 us; speedup vs baseline: 1.4022x; 1.0012x over previous
//
#include <hip/hip_runtime.h>
#include <stdint.h>

typedef unsigned short u16;
typedef __bf16 bf16x8 __attribute__((ext_vector_type(8)));
typedef float  f32x4  __attribute__((ext_vector_type(4)));

// ---- problem constants ----
#define SDIM 2048
#define BDIM 8
#define DIN  1024
#define DOUT 4096
#define EDIM 8
#define RDIM 16
#define KAUG 1152            // DIN + E*R
#define MDIM (SDIM*BDIM)     // 16384
#define SCH  32
#define NT2  18              // K-tiles of 64 for the main GEMM

__device__ __forceinline__ u16 f2bf(float f) {
    __bf16 h = (__bf16)f;
    return __builtin_bit_cast(u16, h);
}

__device__ __forceinline__ void gload16(const u16* g, u16* lds) {
    __builtin_amdgcn_global_load_lds(
        (const __attribute__((address_space(1))) void*)g,
        (__attribute__((address_space(3))) void*)lds, 16, 0, 0);
}

#define VMCNT(n)  asm volatile("s_waitcnt vmcnt(" #n ")" ::: "memory")
#define BARF()    do { asm volatile("" ::: "memory");                \
                       __builtin_amdgcn_s_barrier();                 \
                       asm volatile("" ::: "memory"); } while (0)

// ---------------------------------------------------------------------------
// k1: per-(b, s-chunk) partial sums of x over s + bf16 convert into Xb
// ---------------------------------------------------------------------------
__global__ __launch_bounds__(256) void k1_reduce_convert(
    const float* __restrict__ x, u16* __restrict__ Xb, float* __restrict__ P)
{
    const int b  = blockIdx.x;
    const int sc = blockIdx.y;
    const int i  = threadIdx.x * 4;
    float a0 = 0.f, a1 = 0.f, a2 = 0.f, a3 = 0.f;
    const int s0 = sc * (SDIM / SCH);
    for (int s = s0; s < s0 + (SDIM / SCH); ++s) {
        const float4 v = *reinterpret_cast<const float4*>(
            &x[((size_t)s * BDIM + b) * DIN + i]);
        a0 += v.x; a1 += v.y; a2 += v.z; a3 += v.w;
        ushort4 u{f2bf(v.x), f2bf(v.y), f2bf(v.z), f2bf(v.w)};
        *reinterpret_cast<ushort4*>(&Xb[((size_t)s * BDIM + b) * KAUG + i]) = u;
    }
    float4 p{a0, a1, a2, a3};
    *reinterpret_cast<float4*>(&P[((size_t)sc * BDIM + b) * DIN + i]) = p;
}

// ---------------------------------------------------------------------------
// k2: gate weights
// ---------------------------------------------------------------------------
__global__ __launch_bounds__(256) void k2_gates(
    const float* __restrict__ P, const float* __restrict__ gw,
    const float* __restrict__ gb, float* __restrict__ g)
{
    const int e = blockIdx.x, b = blockIdx.y, t = threadIdx.x;
    float dot = 0.f;
    for (int i = t; i < DIN; i += 256) {
        float xs = 0.f;
        #pragma unroll
        for (int c = 0; c < SCH; ++c) xs += P[((size_t)c * BDIM + b) * DIN + i];
        dot += xs * gw[(size_t)e * DIN + i];
    }
    __shared__ float red[256];
    red[t] = dot;
    __syncthreads();
    #pragma unroll
    for (int off = 128; off > 0; off >>= 1) {
        if (t < off) red[t] += red[t + off];
        __syncthreads();
    }
    if (t == 0) g[b * EDIM + e] = red[0] * (1.0f / SDIM) + gb[e];
}

// ---------------------------------------------------------------------------
// kw: build Waug
// ---------------------------------------------------------------------------
__global__ __launch_bounds__(256) void kw_build_waug(
    const float* __restrict__ W, const float* __restrict__ lb, u16* __restrict__ Waug)
{
    const int o = blockIdx.x, t = threadIdx.x;
    for (int i = t; i < DIN; i += 256)
        Waug[(size_t)o * KAUG + i] = f2bf(W[(size_t)o * DIN + i]);
    if (t < EDIM * RDIM) {
        const int e = t >> 4, r = t & 15;
        Waug[(size_t)o * KAUG + DIN + t] =
            f2bf(lb[((size_t)e * DOUT + o) * RDIM + r]);
    }
}

__global__ __launch_bounds__(256) void kl_convert(
    const float* __restrict__ la, u16* __restrict__ LAb)
{
    const int idx = blockIdx.x * 256 + threadIdx.x;
    if (idx < EDIM * RDIM * DIN) LAb[idx] = f2bf(la[idx]);
}

__global__ __launch_bounds__(256) void k4_scale_u(
    const float* __restrict__ T, const float* __restrict__ g, u16* __restrict__ Xb)
{
    const int idx = blockIdx.x * 256 + threadIdx.x;
    const int m = idx >> 7, er = idx & 127;
    const int b = m & (BDIM - 1), e = er >> 4;
    const float u = g[b * EDIM + e] * T[idx];
    Xb[(size_t)m * KAUG + DIN + er] = f2bf(u);
}

// ---------------------------------------------------------------------------
// gemm_bt: 128x128 tile, BK=64 — small LoRA GEMM (N=128). R6 layout.
// ---------------------------------------------------------------------------
template <int ADD_BIAS>
__global__ __launch_bounds__(256) void gemm_bt(
    const u16* __restrict__ A, int lda,
    const u16* __restrict__ B, int ldb,
    float* __restrict__ C, int ldc,
    const float* __restrict__ bias, int ktiles)
{
    __shared__ __align__(16) u16 As[128][64];
    __shared__ __align__(16) u16 Bs[128][64];

    const int tid  = threadIdx.x;
    const int lane = tid & 63;
    const int l15  = lane & 15;
    const int l4   = lane >> 4;
    const int sw   = lane & 7;
    const int wid  = tid >> 6;
    const int wr   = wid >> 1;
    const int wc   = wid & 1;
    const int m0 = blockIdx.y * 128;
    const int n0 = blockIdx.x * 128;

    f32x4 acc[4][4] = {};

    for (int kt = 0; kt < ktiles; ++kt) {
        #pragma unroll
        for (int ii = 0; ii < 4; ++ii) {
            const int cix = ii * 256 + tid;
            const int row = cix >> 3, cl = cix & 7;
            const int kof = kt * 64 + ((cl ^ (row & 7)) << 3);
            gload16(A + (size_t)(m0 + row) * lda + kof, &As[0][0] + cix * 8);
            gload16(B + (size_t)(n0 + row) * ldb + kof, &Bs[0][0] + cix * 8);
        }
        __syncthreads();
        #pragma unroll
        for (int ks = 0; ks < 2; ++ks) {
            bf16x8 av[4], bv[4];
            #pragma unroll
            for (int mi = 0; mi < 4; ++mi)
                av[mi] = *reinterpret_cast<const bf16x8*>(
                    &As[wr * 64 + mi * 16 + l15][((ks * 4 + l4) ^ sw) << 3]);
            #pragma unroll
            for (int ni = 0; ni < 4; ++ni)
                bv[ni] = *reinterpret_cast<const bf16x8*>(
                    &Bs[wc * 64 + ni * 16 + l15][((ks * 4 + l4) ^ sw) << 3]);
            #pragma unroll
            for (int mi = 0; mi < 4; ++mi)
                #pragma unroll
                for (int ni = 0; ni < 4; ++ni)
                    acc[mi][ni] = __builtin_amdgcn_mfma_f32_16x16x32_bf16(
                        av[mi], bv[ni], acc[mi][ni], 0, 0, 0);
        }
        __syncthreads();
    }

    #pragma unroll
    for (int mi = 0; mi < 4; ++mi) {
        const int r0 = m0 + wr * 64 + mi * 16 + l4 * 4;
        #pragma unroll
        for (int ni = 0; ni < 4; ++ni) {
            const int col = n0 + wc * 64 + ni * 16 + l15;
            const float badd = ADD_BIAS ? bias[col] : 0.0f;
            float* cp = C + (size_t)r0 * ldc + col;
            #pragma unroll
            for (int r = 0; r < 4; ++r)
                cp[(size_t)r * ldc] = acc[mi][ni][r] + badd;
        }
    }
}

// ---------------------------------------------------------------------------
// gemm_main R9: R8 structure + read-ahead pipelining of ds_reads.
// BM=BN=256, BK=64, NT2=18, 512 thr (8 waves 2Mx4N), dbuf LDS 128 KiB,
// coalesced staging layout + (row&7) chunk-XOR swizzle (R8-verified:
// MfmaUtil 29.5->39%, 215->170us).
// R9 change: A-quadrant ds_reads issue ONE PHASE AHEAD into alternating
// register banks (aqA/aqB), so p1..p3's MFMA has no lgkm dependency on
// this-phase reads; read latency hides under the MFMA cluster. Only p0
// (q0+bv of a fresh tile) keeps a direct dependency (once per K-tile).
//   p0: rd bv+q0(dep)+q1(ahead); stage 4j+5; MFMA q0(aqA)   | bar
//   p1: rd q2->aqA;              stage 4j+6; MFMA q1(aqB)   | bar
//   p2: rd q3->aqB;              stage 4j+7; MFMA q2(aqA)   | bar
//   p3: (no reads)               stage 4j+8; MFMA q3(aqB); VMCNT gate | bar
// vmcnt ledger / WAR / gate placement identical to R8 (validated):
// VMCNT(2) at p3 leaves unit 4j+8 in flight, confirms tile j+1 (<=4j+7);
// barrier makes it global before p0(j+1) reads. Tail j>=NT2-2: VMCNT(0).
// ---------------------------------------------------------------------------
__global__ __launch_bounds__(512) void gemm_main(
    const u16* __restrict__ A, const u16* __restrict__ Bm,
    float* __restrict__ C, const float* __restrict__ bias)
{
    __shared__ __align__(16) u16 As[2][2][128][64];   // [buf][Mhalf][row][k] 64 KiB
    __shared__ __align__(16) u16 Bs[2][2][128][64];   // [buf][Nhalf][row][k] 64 KiB

    const int tid  = threadIdx.x;
    const int lane = tid & 63;
    const int l15  = lane & 15;
    const int l4   = lane >> 4;
    const int sw   = lane & 7;
    const int wid  = tid >> 6;      // 0..7
    const int wm   = wid >> 2;      // 0..1  (128-row half)
    const int wn   = wid & 3;       // 0..3  (64-col quarter)
    const int bh   = wn >> 1;       // B Nhalf
    const int bl   = wn & 1;        // 64-row block within half

    // T1: XCD-aware swizzle (nwg = 16*64 = 1024, % 8 == 0)
    const int f   = blockIdx.x + blockIdx.y * gridDim.x;
    const int cpx = (gridDim.x * gridDim.y) >> 3;
    const int s_  = (f & 7) * cpx + (f >> 3);
    const int m0  = (s_ / gridDim.x) * 256;
    const int n0  = (s_ % gridDim.x) * 256;

    f32x4  acc[8][4] = {};
    bf16x8 aqA[2][2], aqB[2][2], bv[4][2];

    auto stage = [&](int s) {
        const int t = s >> 2, part = s & 3, buf = t & 1, hf = part & 1;
        #pragma unroll
        for (int ii = 0; ii < 2; ++ii) {
            const int cix = ii * 512 + tid;
            const int row = cix >> 3, cl = cix & 7;
            const int kof = t * 64 + ((cl ^ (row & 7)) << 3);
            if (part < 2)
                gload16(A + (size_t)(m0 + hf * 128 + row) * KAUG + kof,
                        &As[buf][hf][0][0] + cix * 8);
            else
                gload16(Bm + (size_t)(n0 + hf * 128 + row) * KAUG + kof,
                        &Bs[buf][hf][0][0] + cix * 8);
        }
    };

    #define STG(SU) do { const int su_ = (SU); if (su_ < 4 * NT2) stage(su_); } while (0)
    #define RD_BV(BUF)                                                        \
        _Pragma("unroll") for (int nf = 0; nf < 4; ++nf)                      \
            _Pragma("unroll") for (int kk = 0; kk < 2; ++kk)                  \
                bv[nf][kk] = *reinterpret_cast<const bf16x8*>(                \
                    &Bs[BUF][bh][bl * 64 + nf * 16 + l15]                     \
                       [((kk * 4 + l4) ^ sw) << 3]);
    #define RD_AQ(BUF, Q, DST)                                                \
        _Pragma("unroll") for (int fr = 0; fr < 2; ++fr)                      \
            _Pragma("unroll") for (int kk = 0; kk < 2; ++kk)                  \
                DST[fr][kk] = *reinterpret_cast<const bf16x8*>(               \
                    &As[BUF][wm][(Q) * 32 + fr * 16 + l15]                    \
                       [((kk * 4 + l4) ^ sw) << 3]);
    #define MMA(SRC, Q)                                                       \
        do {                                                                  \
            __builtin_amdgcn_s_setprio(1);                                    \
            _Pragma("unroll") for (int kk = 0; kk < 2; ++kk)                  \
                _Pragma("unroll") for (int fr = 0; fr < 2; ++fr)              \
                    _Pragma("unroll") for (int nf = 0; nf < 4; ++nf)          \
                        acc[(Q) * 2 + fr][nf] =                               \
                            __builtin_amdgcn_mfma_f32_16x16x32_bf16(          \
                                SRC[fr][kk], bv[nf][kk],                      \
                                acc[(Q) * 2 + fr][nf], 0, 0, 0);              \
            __builtin_amdgcn_s_setprio(0);                                    \
        } while (0)

    // prologue: units 0..4 (tile 0 fully + A-h0 of tile 1) = 10 gloads
    stage(0); stage(1); stage(2); stage(3); stage(4);
    VMCNT(2);                       // confirm units 0..3 (tile 0); unit 4 in flight
    BARF();

    for (int j = 0; j < NT2; ++j) {
        const int buf = j & 1;
        // ---- p0: bv+q0 (direct dep) + q1 (read-ahead) ----
        RD_BV(buf);
        RD_AQ(buf, 0, aqA);
        RD_AQ(buf, 1, aqB);
        STG(4 * j + 5);
        MMA(aqA, 0);
        BARF();
        // ---- p1: read q2 ahead; MFMA q1 (no lgkm dep) ----
        RD_AQ(buf, 2, aqA);
        STG(4 * j + 6);
        MMA(aqB, 1);
        BARF();
        // ---- p2: read q3 ahead; MFMA q2 ----
        RD_AQ(buf, 3, aqB);
        STG(4 * j + 7);
        MMA(aqA, 2);
        BARF();
        // ---- p3: no reads; MFMA q3; vmcnt gate ----
        STG(4 * j + 8);
        MMA(aqB, 3);
        if (j < NT2 - 2) { VMCNT(2); } else { VMCNT(0); }
        BARF();
    }
    #undef STG
    #undef RD_BV
    #undef RD_AQ
    #undef MMA

    // ---- epilogue: row = wm*128 + a*16 + l4*4, col per fragment ----
    #pragma unroll
    for (int a = 0; a < 8; ++a) {
        const int row0 = m0 + wm * 128 + a * 16 + l4 * 4;
        #pragma unroll
        for (int nf = 0; nf < 4; ++nf) {
            const int col = n0 + wn * 64 + nf * 16 + l15;
            const float badd = bias[col];
            float* cp = C + (size_t)row0 * DOUT + col;
            #pragma unroll
            for (int q = 0; q < 4; ++q)
                cp[(size_t)q * DOUT] = acc[a][nf][q] + badd;
        }
    }
}

// ---------------------------------------------------------------------------
extern "C" void kernel_launch(void* const* d_in, const int* in_sizes, int n_in,
                              void* d_out, int out_size, void* d_ws, size_t ws_size,
                              hipStream_t stream)
{
    const float* x    = (const float*)d_in[0];
    const float* gw   = (const float*)d_in[1];
    const float* gb   = (const float*)d_in[2];
    const float* W    = (const float*)d_in[3];
    const float* bias = (const float*)d_in[4];
    const float* la   = (const float*)d_in[5];
    const float* lb   = (const float*)d_in[6];
    float* out = (float*)d_out;

    char* ws = (char*)d_ws;
    u16*   Xb   = (u16*)(ws);                       // 37,748,736 B
    u16*   Waug = (u16*)(ws + 37748736);            //  9,437,184 B
    float* T    = (float*)(ws + 47185920);          //  8,388,608 B
    float* P    = (float*)(ws + 55574528);          //  1,048,576 B
    u16*   LAb  = (u16*)(ws + 56623104);            //    262,144 B
    float* G    = (float*)(ws + 56885248);          //        256 B

    k1_reduce_convert<<<dim3(BDIM, SCH), 256, 0, stream>>>(x, Xb, P);
    kw_build_waug<<<DOUT, 256, 0, stream>>>(W, lb, Waug);
    kl_convert<<<(EDIM * RDIM * DIN + 255) / 256, 256, 0, stream>>>(la, LAb);
    k2_gates<<<dim3(EDIM, BDIM), 256, 0, stream>>>(P, gw, gb, G);
    gemm_bt<0><<<dim3(1, MDIM / 128), 256, 0, stream>>>(
        Xb, KAUG, LAb, DIN, T, EDIM * RDIM, nullptr, DIN / 64);
    k4_scale_u<<<(MDIM * EDIM * RDIM) / 256, 256, 0, stream>>>(T, G, Xb);
    gemm_main<<<dim3(DOUT / 256, MDIM / 256), 512, 0, stream>>>(
        Xb, Waug, out, bias);
}